// Round 3
// baseline (1140.976 us; speedup 1.0000x reference)
//
#include <hip/hip_runtime.h>
#include <hip/hip_bf16.h>
#include <math.h>

#define NNODES 100000
#define NEDGES 1600000
#define EN     1700000      // edges + self loops
#define F_IN   256
#define F_MID  128
#define HID    128
#define NG     128
#define NOUT   64
#define SCAN_CHUNK 2048
#define NCHUNK ((NNODES + SCAN_CHUNK - 1) / SCAN_CHUNK)   // 49

typedef unsigned int  u32;
typedef unsigned short u16;

__device__ __forceinline__ float bfl(u32 u) { return __uint_as_float(u << 16); }
__device__ __forceinline__ float bfh(u32 u) { return __uint_as_float(u & 0xFFFF0000u); }
__device__ __forceinline__ u32 f2bf(float f) {           // round-to-nearest-even
    u32 x = __float_as_uint(f);
    return (x + 0x7FFFu + ((x >> 16) & 1u)) >> 16;
}

// ---------------------------------------------------------------- init
__global__ __launch_bounds__(256) void k_init(int* deg, float* gs, float* pooled) {
    int i = blockIdx.x * 256 + threadIdx.x;
    if (i < NNODES) deg[i] = 1;                 // self loop
    if (i < NG) gs[i] = 0.f;
    if (i < NG * HID) pooled[i] = 0.f;
}

// ---------------------------------------------------------------- CSR build
__global__ __launch_bounds__(256) void k_count(const int* __restrict__ ei, int* deg) {
    int e = blockIdx.x * 256 + threadIdx.x;
    if (e >= NEDGES) return;
    atomicAdd(&deg[ei[NEDGES + e]], 1);
}

__global__ __launch_bounds__(256) void k_scan_chunk(const int* __restrict__ deg,
                                                    int* rowptr, int* part) {
    __shared__ int sums[256];
    int c = blockIdx.x, t = threadIdx.x;
    int base = c * SCAN_CHUNK;
    int v[8]; int s = 0;
#pragma unroll
    for (int i = 0; i < 8; i++) {
        int idx = base + t * 8 + i;
        v[i] = (idx < NNODES) ? deg[idx] : 0;
        s += v[i];
    }
    sums[t] = s;
    __syncthreads();
    for (int off = 1; off < 256; off <<= 1) {
        int x = (t >= off) ? sums[t - off] : 0;
        __syncthreads();
        sums[t] += x;
        __syncthreads();
    }
    int run = (t == 0) ? 0 : sums[t - 1];
#pragma unroll
    for (int i = 0; i < 8; i++) {
        int idx = base + t * 8 + i;
        if (idx < NNODES) rowptr[idx] = run;
        run += v[i];
    }
    if (t == 255) part[c] = sums[255];
}

__global__ void k_scan_part(int* part, int nc) {
    if (threadIdx.x == 0) {
        int run = 0;
        for (int c = 0; c < nc; c++) { int v = part[c]; part[c] = run; run += v; }
    }
}

__global__ __launch_bounds__(256) void k_scan_add(int* rowptr, int* cursor,
                                                  const int* __restrict__ part) {
    int i = blockIdx.x * 256 + threadIdx.x;
    if (i >= NNODES) return;
    int v = rowptr[i] + part[i >> 11];
    rowptr[i] = v;
    cursor[i] = v;
}

__global__ __launch_bounds__(256) void k_fill(const int* __restrict__ ei,
                                              int* cursor, int* srcs) {
    int e = blockIdx.x * 256 + threadIdx.x;
    if (e >= EN) return;
    int src, dst;
    if (e < NEDGES) { src = ei[e]; dst = ei[NEDGES + e]; }
    else            { src = dst = e - NEDGES; }
    int pos = atomicAdd(&cursor[dst], 1);
    srcs[pos] = src;
}

// ---------------------------------------------------------------- GEMM (C[M,128] = A[M,K] @ B[K,128]) -> bf16 C
template <int K, bool ABF>
__global__ __launch_bounds__(256) void k_gemm(const void* __restrict__ Av,
                                              const float* __restrict__ B,
                                              u16* __restrict__ C, int M) {
    __shared__ float As[16][128];
    __shared__ float Bs[16][128];
    int bm = blockIdx.x * 128;
    int tid = threadIdx.x;
    int tx = tid & 15, ty = tid >> 4;
    float acc[8][8] = {};
    for (int k0 = 0; k0 < K; k0 += 16) {
#pragma unroll
        for (int q = tid; q < 512; q += 256) {       // A tile -> As[k][m] (transposed)
            int m = q >> 2, kq = (q & 3) << 2;
            int row = bm + m;
            if (ABF) {
                const u16* A = (const u16*)Av;
                uint2 v = make_uint2(0u, 0u);
                if (row < M) v = *(const uint2*)(A + (size_t)row * K + k0 + kq);
                As[kq + 0][m] = bfl(v.x); As[kq + 1][m] = bfh(v.x);
                As[kq + 2][m] = bfl(v.y); As[kq + 3][m] = bfh(v.y);
            } else {
                const float* A = (const float*)Av;
                float4 v = make_float4(0.f, 0.f, 0.f, 0.f);
                if (row < M) v = *(const float4*)(A + (size_t)row * K + k0 + kq);
                As[kq + 0][m] = v.x; As[kq + 1][m] = v.y;
                As[kq + 2][m] = v.z; As[kq + 3][m] = v.w;
            }
        }
#pragma unroll
        for (int q = tid; q < 512; q += 256) {       // B tile
            int kk = q >> 5, n4 = (q & 31) << 2;
            *(float4*)(&Bs[kk][n4]) = *(const float4*)(B + (size_t)(k0 + kk) * 128 + n4);
        }
        __syncthreads();
#pragma unroll
        for (int kk = 0; kk < 16; kk++) {
            float a[8], b[8];
            *(float4*)(a)     = *(float4*)(&As[kk][ty * 8]);
            *(float4*)(a + 4) = *(float4*)(&As[kk][ty * 8 + 4]);
            *(float4*)(b)     = *(float4*)(&Bs[kk][tx * 8]);
            *(float4*)(b + 4) = *(float4*)(&Bs[kk][tx * 8 + 4]);
#pragma unroll
            for (int i = 0; i < 8; i++)
#pragma unroll
                for (int j = 0; j < 8; j++)
                    acc[i][j] = fmaf(a[i], b[j], acc[i][j]);
        }
        __syncthreads();
    }
#pragma unroll
    for (int i = 0; i < 8; i++) {
        int row = bm + ty * 8 + i;
        if (row < M) {
            uint4 o;
            o.x = f2bf(acc[i][0]) | (f2bf(acc[i][1]) << 16);
            o.y = f2bf(acc[i][2]) | (f2bf(acc[i][3]) << 16);
            o.z = f2bf(acc[i][4]) | (f2bf(acc[i][5]) << 16);
            o.w = f2bf(acc[i][6]) | (f2bf(acc[i][7]) << 16);
            *(uint4*)(C + (size_t)row * 128 + tx * 8) = o;
        }
    }
}

// ---------------------------------------------------------------- attention dot products (wave per node, bf16 h)
__global__ __launch_bounds__(256) void k_dots(const u32* __restrict__ h,
                                              const float* __restrict__ asrc,
                                              const float* __restrict__ adst,
                                              float* as_, float* ad_) {
    int wid = (blockIdx.x * 256 + threadIdx.x) >> 6;
    int lane = threadIdx.x & 63;
    if (wid >= NNODES) return;
    u32 u = h[(size_t)wid * 64 + lane];
    float vx = bfl(u), vy = bfh(u);
    float2 as2 = ((const float2*)asrc)[lane];
    float2 ad2 = ((const float2*)adst)[lane];
    float s = vx * as2.x + vy * as2.y;
    float d = vx * ad2.x + vy * ad2.y;
#pragma unroll
    for (int off = 32; off; off >>= 1) {
        s += __shfl_xor(s, off);
        d += __shfl_xor(d, off);
    }
    if (lane == 0) { as_[wid] = s; ad_[wid] = d; }
}

// ---------------------------------------------------------------- GAT aggregation (wave per dst node, bf16 h payload)
// softmax without max subtraction (shift-invariant; logits O(1) for this input).
// Lane owns features {2*lane, 2*lane+1} packed in one dword. 8-wide edge unroll.
template <bool RELU, bool GATE, bool OUTBF>
__global__ __launch_bounds__(256) void k_agg(
    const u32* __restrict__ h, const float* __restrict__ as_,
    const float* __restrict__ ad_, const int* __restrict__ rowptr,
    const int* __restrict__ rowend, const int* __restrict__ srcs,
    const float* __restrict__ bias, void* __restrict__ outv,
    const float* __restrict__ gateW, const float* __restrict__ gateB,
    float* __restrict__ gatev, float* __restrict__ gs,
    const int* __restrict__ batch) {
    int wid = (blockIdx.x * 256 + threadIdx.x) >> 6;
    int lane = threadIdx.x & 63;
    if (wid >= NNODES) return;
    int row = rowptr[wid];
    int dg = rowend[wid] - row;
    float adn = ad_[wid];

    float ssum = 0.f;
    float2 a0 = {0.f, 0.f}, a1 = {0.f, 0.f}, a2 = {0.f, 0.f}, a3 = {0.f, 0.f};
    float2 a4 = {0.f, 0.f}, a5 = {0.f, 0.f}, a6 = {0.f, 0.f}, a7 = {0.f, 0.f};

    for (int base = 0; base < dg; base += 64) {
        int k = base + lane;
        float ev = 0.f; int sk = 0;
        if (k < dg) {
            sk = srcs[row + k];
            float al = as_[sk] + adn;
            al = (al > 0.f) ? al : 0.2f * al;
            ev = __expf(al);
            ssum += ev;
        }
        int rem = dg - base; if (rem > 64) rem = 64;
        int kk = 0;
        for (; kk + 8 <= rem; kk += 8) {
            int   s0 = __shfl(sk, kk + 0), s1 = __shfl(sk, kk + 1);
            int   s2 = __shfl(sk, kk + 2), s3 = __shfl(sk, kk + 3);
            int   s4 = __shfl(sk, kk + 4), s5 = __shfl(sk, kk + 5);
            int   s6 = __shfl(sk, kk + 6), s7 = __shfl(sk, kk + 7);
            float e0 = __shfl(ev, kk + 0), e1 = __shfl(ev, kk + 1);
            float e2 = __shfl(ev, kk + 2), e3 = __shfl(ev, kk + 3);
            float e4 = __shfl(ev, kk + 4), e5 = __shfl(ev, kk + 5);
            float e6 = __shfl(ev, kk + 6), e7 = __shfl(ev, kk + 7);
            u32 u0 = h[(size_t)s0 * 64 + lane];
            u32 u1 = h[(size_t)s1 * 64 + lane];
            u32 u2 = h[(size_t)s2 * 64 + lane];
            u32 u3 = h[(size_t)s3 * 64 + lane];
            u32 u4 = h[(size_t)s4 * 64 + lane];
            u32 u5 = h[(size_t)s5 * 64 + lane];
            u32 u6 = h[(size_t)s6 * 64 + lane];
            u32 u7 = h[(size_t)s7 * 64 + lane];
            a0.x = fmaf(e0, bfl(u0), a0.x); a0.y = fmaf(e0, bfh(u0), a0.y);
            a1.x = fmaf(e1, bfl(u1), a1.x); a1.y = fmaf(e1, bfh(u1), a1.y);
            a2.x = fmaf(e2, bfl(u2), a2.x); a2.y = fmaf(e2, bfh(u2), a2.y);
            a3.x = fmaf(e3, bfl(u3), a3.x); a3.y = fmaf(e3, bfh(u3), a3.y);
            a4.x = fmaf(e4, bfl(u4), a4.x); a4.y = fmaf(e4, bfh(u4), a4.y);
            a5.x = fmaf(e5, bfl(u5), a5.x); a5.y = fmaf(e5, bfh(u5), a5.y);
            a6.x = fmaf(e6, bfl(u6), a6.x); a6.y = fmaf(e6, bfh(u6), a6.y);
            a7.x = fmaf(e7, bfl(u7), a7.x); a7.y = fmaf(e7, bfh(u7), a7.y);
        }
        for (; kk + 2 <= rem; kk += 2) {
            int   s0 = __shfl(sk, kk + 0), s1 = __shfl(sk, kk + 1);
            float e0 = __shfl(ev, kk + 0), e1 = __shfl(ev, kk + 1);
            u32 u0 = h[(size_t)s0 * 64 + lane];
            u32 u1 = h[(size_t)s1 * 64 + lane];
            a0.x = fmaf(e0, bfl(u0), a0.x); a0.y = fmaf(e0, bfh(u0), a0.y);
            a1.x = fmaf(e1, bfl(u1), a1.x); a1.y = fmaf(e1, bfh(u1), a1.y);
        }
        if (kk < rem) {
            int   s0 = __shfl(sk, kk);
            float e0 = __shfl(ev, kk);
            u32 u0 = h[(size_t)s0 * 64 + lane];
            a0.x = fmaf(e0, bfl(u0), a0.x); a0.y = fmaf(e0, bfh(u0), a0.y);
        }
    }
    float2 acc;
    acc.x = ((a0.x + a1.x) + (a2.x + a3.x)) + ((a4.x + a5.x) + (a6.x + a7.x));
    acc.y = ((a0.y + a1.y) + (a2.y + a3.y)) + ((a4.y + a5.y) + (a6.y + a7.y));
#pragma unroll
    for (int off = 32; off; off >>= 1) ssum += __shfl_xor(ssum, off);
    float inv = 1.f / (ssum + 1e-16f);
    float2 b2v = ((const float2*)bias)[lane];
    float o0 = acc.x * inv + b2v.x;
    float o1 = acc.y * inv + b2v.y;
    if (RELU) { o0 = fmaxf(o0, 0.f); o1 = fmaxf(o1, 0.f); }
    if (OUTBF) {
        ((u32*)outv)[(size_t)wid * 64 + lane] = f2bf(o0) | (f2bf(o1) << 16);
    } else {
        ((float2*)((float*)outv + (size_t)wid * 128))[lane] = make_float2(o0, o1);
    }
    if (GATE) {
        float2 gw = ((const float2*)gateW)[lane];
        float g = o0 * gw.x + o1 * gw.y;
#pragma unroll
        for (int off = 32; off; off >>= 1) g += __shfl_xor(g, off);
        if (lane == 0) {
            float ge = __expf(g + gateB[0]);   // no max subtraction (shift-invariant)
            gatev[wid] = ge;
            atomicAdd(&gs[batch[wid]], ge);
        }
    }
}

// ---------------------------------------------------------------- attention pooling (batch is sorted)
__global__ __launch_bounds__(128) void k_pool(const float* __restrict__ h,
                                              const float* __restrict__ gatev,
                                              const float* __restrict__ gs,
                                              const int* __restrict__ batch,
                                              float* pooled) {
    int t = threadIdx.x;  // feature
    int chunk = (NNODES + gridDim.x - 1) / gridDim.x;
    int s0 = blockIdx.x * chunk;
    int s1 = s0 + chunk; if (s1 > NNODES) s1 = NNODES;
    if (s0 >= s1) return;
    int curg = batch[s0];
    float invs = 1.f / (gs[curg] + 1e-16f);
    float acc = 0.f;
    for (int i = s0; i < s1; i++) {
        int g = batch[i];
        if (g != curg) {
            atomicAdd(&pooled[curg * 128 + t], acc);
            acc = 0.f; curg = g;
            invs = 1.f / (gs[g] + 1e-16f);
        }
        acc += h[(size_t)i * 128 + t] * (gatev[i] * invs);
    }
    atomicAdd(&pooled[curg * 128 + t], acc);
}

// ---------------------------------------------------------------- final: relu(pooled) @ lin_W + lin_b
__global__ __launch_bounds__(64) void k_final(const float* __restrict__ pooled,
                                              const float* __restrict__ linW,
                                              const float* __restrict__ linb,
                                              float* __restrict__ out) {
    __shared__ float rowv[128];
    int g = blockIdx.x, t = threadIdx.x;
    rowv[t]      = fmaxf(pooled[g * 128 + t], 0.f);
    rowv[t + 64] = fmaxf(pooled[g * 128 + 64 + t], 0.f);
    __syncthreads();
    float acc = linb[t];
#pragma unroll 8
    for (int k = 0; k < 128; k++) acc = fmaf(rowv[k], linW[k * 64 + t], acc);
    out[g * 64 + t] = acc;
}

// ---------------------------------------------------------------- launch
extern "C" void kernel_launch(void* const* d_in, const int* in_sizes, int n_in,
                              void* d_out, int out_size, void* d_ws, size_t ws_size,
                              hipStream_t stream) {
    const float* x     = (const float*)d_in[0];
    const int*   ei    = (const int*)d_in[1];
    const int*   batch = (const int*)d_in[2];
    const float* W1    = (const float*)d_in[3];
    const float* a1s   = (const float*)d_in[4];
    const float* a1d   = (const float*)d_in[5];
    const float* b1    = (const float*)d_in[6];
    const float* W2    = (const float*)d_in[7];
    const float* a2s   = (const float*)d_in[8];
    const float* a2d   = (const float*)d_in[9];
    const float* b2    = (const float*)d_in[10];
    const float* gateW = (const float*)d_in[11];
    const float* gateB = (const float*)d_in[12];
    const float* linW  = (const float*)d_in[13];
    const float* linb  = (const float*)d_in[14];
    float* out = (float*)d_out;

    char* p = (char*)d_ws;
    auto alloc = [&](size_t bytes) -> void* {
        void* r = (void*)p;
        p += (bytes + 255) & ~(size_t)255;
        return r;
    };
    u16*   hb     = (u16*)alloc((size_t)NNODES * 128 * 2);   // GEMM out (bf16): h1 then h2
    u16*   h1a    = (u16*)alloc((size_t)NNODES * 128 * 2);   // conv1 agg out (bf16)
    float* bufF   = (float*)alloc((size_t)NNODES * 128 * 4); // conv2 agg out (fp32)
    float* as_    = (float*)alloc((size_t)NNODES * 4);
    float* ad_    = (float*)alloc((size_t)NNODES * 4);
    float* gatev  = (float*)alloc((size_t)NNODES * 4);
    int*   deg    = (int*)alloc((size_t)NNODES * 4);
    int*   rowptr = (int*)alloc((size_t)NNODES * 4);
    int*   cursor = (int*)alloc((size_t)NNODES * 4);
    int*   srcs   = (int*)alloc((size_t)EN * 4);
    int*   part   = (int*)alloc(64 * 4);
    float* gs     = (float*)alloc(NG * 4);
    float* pooled = (float*)alloc((size_t)NG * HID * 4);

    const int gN   = (NNODES + 255) / 256;        // 391
    const int gE   = (NEDGES + 255) / 256;
    const int gEN  = (EN + 255) / 256;
    const int gW   = (NNODES + 3) / 4;            // wave-per-node, 4 waves/block

    // CSR build (same graph for both convs)
    k_init<<<gN, 256, 0, stream>>>(deg, gs, pooled);
    k_count<<<gE, 256, 0, stream>>>(ei, deg);
    k_scan_chunk<<<NCHUNK, 256, 0, stream>>>(deg, rowptr, part);
    k_scan_part<<<1, 64, 0, stream>>>(part, NCHUNK);
    k_scan_add<<<gN, 256, 0, stream>>>(rowptr, cursor, part);
    k_fill<<<gEN, 256, 0, stream>>>(ei, cursor, srcs);
    // after k_fill, cursor[n] == row end

    // conv1 (payload bf16)
    k_gemm<256, false><<<(NNODES + 127) / 128, 256, 0, stream>>>(x, W1, hb, NNODES);
    k_dots<<<gW, 256, 0, stream>>>((const u32*)hb, a1s, a1d, as_, ad_);
    k_agg<true, false, true><<<gW, 256, 0, stream>>>((const u32*)hb, as_, ad_,
                                                     rowptr, cursor, srcs, b1, h1a,
                                                     nullptr, nullptr, nullptr,
                                                     nullptr, nullptr);
    // conv2 (bf16 A GEMM, fp32 agg out, fused gate)
    k_gemm<128, true><<<(NNODES + 127) / 128, 256, 0, stream>>>(h1a, W2, hb, NNODES);
    k_dots<<<gW, 256, 0, stream>>>((const u32*)hb, a2s, a2d, as_, ad_);
    k_agg<false, true, false><<<gW, 256, 0, stream>>>((const u32*)hb, as_, ad_,
                                                      rowptr, cursor, srcs, b2, bufF,
                                                      gateW, gateB, gatev, gs, batch);
    // global attention pooling + final linear
    k_pool<<<512, 128, 0, stream>>>(bufF, gatev, gs, batch, pooled);
    k_final<<<NG, 64, 0, stream>>>(pooled, linW, linb, out);
}